// Round 1
// baseline (281.979 us; speedup 1.0000x reference)
//
#include <hip/hip_runtime.h>

// x: (B=16, C=3, H=512, W=512) float32 -> out: (16, 15, 512, 512) float32
// Single-phase, LDS-free rewrite: each thread owns 2 output rows x 4 output
// cols for all 5 bands. Haar coefficients (3 rows x 4 cols neighborhood) are
// computed directly from global loads; column halo comes from two clamped 8B
// loads (L1-hot overlap with neighbor lanes) instead of an LDS round-trip.
// No __syncthreads, no LDS -> pure streaming, max memory-level parallelism.
#define HF   512
#define WF   512
#define HH   256
#define HW   (HF * WF)
#define TK   4      // coef rows per block (output rows = 8)

typedef float v4 __attribute__((ext_vector_type(4)));
typedef float v2 __attribute__((ext_vector_type(2)));

// 2x2 Haar: returns (LL, LH, HL, HH) for one coefficient position
__device__ __forceinline__ v4 haar2(float a, float b, float c, float d) {
    const float s1 = a + b, d1 = a - b, s2 = c + d, d2 = c - d;
    v4 v;
    v.x = (s1 + s2) * 0.5f;   // LL
    v.y = (s1 - s2) * 0.5f;   // LH
    v.z = (d1 + d2) * 0.5f;   // HL
    v.w = (d1 - d2) * 0.5f;   // HH
    return v;
}

__global__ __launch_bounds__(256, 2) void wavelet_kernel(const float* __restrict__ x,
                                                         float* __restrict__ out) {
    const int tx = threadIdx.x;            // 0..63
    const int ty = threadIdx.y;            // 0..3
    const int k  = blockIdx.y * TK + ty;   // coef row 0..255
    const int l0 = blockIdx.x * 128;       // coef col base (half width per block)
    const int bc = blockIdx.z;             // 0..47 (B*C)

    const float* __restrict__ xin  = x   + (size_t)bc * HW;
    float*       __restrict__ outp = out + (size_t)bc * (size_t)(5 * HW);

    // out cols x0..x0+3; coef cols j-1..j+2 where j = l0 + 2*tx, x0 = 2*j
    const int x0 = 2 * l0 + 4 * tx;
    const int xl = (x0 == 0) ? 0 : x0 - 2;                 // left-halo v2 (edge clamp)
    const int xr = (x0 + 4 > WF - 2) ? WF - 2 : x0 + 4;    // right-halo v2 (edge clamp)

    // coef rows k-1, k, k+1 with edge clamp (matches reference's clamped resize)
    const int ku = (k == 0) ? 0 : k - 1;
    const int kd = (k == HH - 1) ? HH - 1 : k + 1;

    const float* p0 = xin + (size_t)(2 * ku) * WF;
    const float* p1 = xin + (size_t)(2 * k)  * WF;
    const float* p2 = xin + (size_t)(2 * kd) * WF;

    // ---- issue all 18 independent loads up front (compiler schedules MLP) ----
    const v4 t0  = *reinterpret_cast<const v4*>(p0 + x0);
    const v4 u0  = *reinterpret_cast<const v4*>(p0 + WF + x0);
    const v2 tl0 = *reinterpret_cast<const v2*>(p0 + xl);
    const v2 ul0 = *reinterpret_cast<const v2*>(p0 + WF + xl);
    const v2 tr0 = *reinterpret_cast<const v2*>(p0 + xr);
    const v2 ur0 = *reinterpret_cast<const v2*>(p0 + WF + xr);

    const v4 t1  = *reinterpret_cast<const v4*>(p1 + x0);
    const v4 u1  = *reinterpret_cast<const v4*>(p1 + WF + x0);
    const v2 tl1 = *reinterpret_cast<const v2*>(p1 + xl);
    const v2 ul1 = *reinterpret_cast<const v2*>(p1 + WF + xl);
    const v2 tr1 = *reinterpret_cast<const v2*>(p1 + xr);
    const v2 ur1 = *reinterpret_cast<const v2*>(p1 + WF + xr);

    const v4 t2  = *reinterpret_cast<const v4*>(p2 + x0);
    const v4 u2  = *reinterpret_cast<const v4*>(p2 + WF + x0);
    const v2 tl2 = *reinterpret_cast<const v2*>(p2 + xl);
    const v2 ul2 = *reinterpret_cast<const v2*>(p2 + WF + xl);
    const v2 tr2 = *reinterpret_cast<const v2*>(p2 + xr);
    const v2 ur2 = *reinterpret_cast<const v2*>(p2 + WF + xr);

    // ---- horizontal interp per coef row, accumulate vertically into ve/vo ----
    // out col 2j   = 0.25*c[j-1] + 0.75*c[j]
    // out col 2j+1 = 0.75*c[j]   + 0.25*c[j+1]
    // out row 2k   = 0.25*hr(k-1) + 0.75*hr(k)
    // out row 2k+1 = 0.75*hr(k)   + 0.25*hr(k+1)
    v4 ve[4], vo[4];
    {   // coef row k-1
        const v4 A = haar2(tl0.x, tl0.y, ul0.x, ul0.y);   // c[j-1]
        const v4 B = haar2(t0.x,  t0.y,  u0.x,  u0.y);    // c[j]
        const v4 C = haar2(t0.z,  t0.w,  u0.z,  u0.w);    // c[j+1]
        const v4 D = haar2(tr0.x, tr0.y, ur0.x, ur0.y);   // c[j+2]
        ve[0] = (A * 0.25f + B * 0.75f) * 0.25f;
        ve[1] = (B * 0.75f + C * 0.25f) * 0.25f;
        ve[2] = (B * 0.25f + C * 0.75f) * 0.25f;
        ve[3] = (C * 0.75f + D * 0.25f) * 0.25f;
    }
    {   // coef row k
        const v4 A = haar2(tl1.x, tl1.y, ul1.x, ul1.y);
        const v4 B = haar2(t1.x,  t1.y,  u1.x,  u1.y);
        const v4 C = haar2(t1.z,  t1.w,  u1.z,  u1.w);
        const v4 D = haar2(tr1.x, tr1.y, ur1.x, ur1.y);
        v4 h;
        h = A * 0.25f + B * 0.75f;  ve[0] += h * 0.75f;  vo[0] = h * 0.75f;
        h = B * 0.75f + C * 0.25f;  ve[1] += h * 0.75f;  vo[1] = h * 0.75f;
        h = B * 0.25f + C * 0.75f;  ve[2] += h * 0.75f;  vo[2] = h * 0.75f;
        h = C * 0.75f + D * 0.25f;  ve[3] += h * 0.75f;  vo[3] = h * 0.75f;
    }
    {   // coef row k+1
        const v4 A = haar2(tl2.x, tl2.y, ul2.x, ul2.y);
        const v4 B = haar2(t2.x,  t2.y,  u2.x,  u2.y);
        const v4 C = haar2(t2.z,  t2.w,  u2.z,  u2.w);
        const v4 D = haar2(tr2.x, tr2.y, ur2.x, ur2.y);
        vo[0] += (A * 0.25f + B * 0.75f) * 0.25f;
        vo[1] += (B * 0.75f + C * 0.25f) * 0.25f;
        vo[2] += (B * 0.25f + C * 0.75f) * 0.25f;
        vo[3] += (C * 0.75f + D * 0.25f) * 0.25f;
    }

    // ---- stores: band 0 identity (reuses center-row loads) + 4 upsampled bands ----
    const int y0 = 2 * k;
    float* o0 = outp + (size_t)y0 * WF + x0;
    __builtin_nontemporal_store(t1, reinterpret_cast<v4*>(o0));
    __builtin_nontemporal_store(u1, reinterpret_cast<v4*>(o0 + WF));

#define STORE_BAND(BIDX, COMP)                                                         \
    {                                                                                  \
        v4 e, o;                                                                       \
        e.x = ve[0].COMP; e.y = ve[1].COMP; e.z = ve[2].COMP; e.w = ve[3].COMP;        \
        o.x = vo[0].COMP; o.y = vo[1].COMP; o.z = vo[2].COMP; o.w = vo[3].COMP;        \
        float* ob = outp + (size_t)BIDX * HW + (size_t)y0 * WF + x0;                   \
        __builtin_nontemporal_store(e, reinterpret_cast<v4*>(ob));                     \
        __builtin_nontemporal_store(o, reinterpret_cast<v4*>(ob + WF));                \
    }
    STORE_BAND(1, x)  // LL
    STORE_BAND(2, y)  // LH
    STORE_BAND(3, z)  // HL
    STORE_BAND(4, w)  // HH
#undef STORE_BAND
}

extern "C" void kernel_launch(void* const* d_in, const int* in_sizes, int n_in,
                              void* d_out, int out_size, void* d_ws, size_t ws_size,
                              hipStream_t stream) {
    const float* x = (const float*)d_in[0];
    float* out = (float*)d_out;
    dim3 grid(2, HH / TK, 48);     // 2 x 64 x 48 = 6144 blocks
    dim3 block(64, TK);            // 256 threads, no LDS, no barrier
    hipLaunchKernelGGL(wavelet_kernel, grid, block, 0, stream, x, out);
}